// Round 8
// baseline (38750.616 us; speedup 1.0000x reference)
//
#include <hip/hip_runtime.h>

typedef _Float16 f16;
typedef _Float16 f16x8 __attribute__((ext_vector_type(8)));
typedef float f32x16 __attribute__((ext_vector_type(16)));

#define HID   512
#define NSTEP 100
#define WMAT  786432      // halfs per packed weight matrix (1536*512)

__device__ __forceinline__ float sigmoid_f(float x) {
  return 1.0f / (1.0f + __expf(-x));
}
__device__ __forceinline__ float tanh_f(float x) {
  float e = __expf(2.0f * x);
  return 1.0f - 2.0f / (e + 1.0f);
}
__device__ __forceinline__ f32x16 mfma16(f16x8 a, f16x8 b, f32x16 c) {
  return __builtin_amdgcn_mfma_f32_32x32x16_f16(a, b, c, 0, 0, 0);
}
__device__ __forceinline__ f32x16 zero16() {
  f32x16 z;
#pragma unroll
  for (int i = 0; i < 16; ++i) z[i] = 0.f;
  return z;
}

// ---- weight pack: fp32 [1536][512] row-major -> B-fragment-packed fp16 ----
// layout [ct(48)][kt(32)][lane(64)][i(8)]:
//   gate = ct*32 + (lane&31), k = kt*16 + (lane>>5)*8 + i
__global__ void pack_weights(const float* __restrict__ W, f16* __restrict__ out) {
  int t = blockIdx.x * 256 + threadIdx.x;
  if (t >= 48 * 32 * 64) return;
  int lane = t & 63;
  int kt   = (t >> 6) & 31;
  int ct   = t >> 11;
  int gate = ct * 32 + (lane & 31);
  int k0   = kt * 16 + (lane >> 5) * 8;
  const float* src = W + gate * HID + k0;
  f16x8 v;
#pragma unroll
  for (int i = 0; i < 8; ++i) v[i] = (f16)src[i];
  *(f16x8*)(out + (size_t)t * 8) = v;
}

// combined biases: [0..1023]=bi+bh (r,z), [1024..1535]=bi_n, [1536..2047]=bh_n
__global__ void pack_bias(const float* __restrict__ bi, const float* __restrict__ bh,
                          float* __restrict__ out) {
  int j = blockIdx.x * 256 + threadIdx.x;
  if (j < 1024)      out[j] = bi[j] + bh[j];
  else if (j < 1536) out[j] = bi[j];
  else if (j < 2048) out[j] = bh[j - 512];
}

// Persistent per-block GRU: 64 batch rows as TWO 32-row tiles sharing every
// B-fragment. 8 waves (2/SIMD, 256-reg budget), wave owns 64 hidden cols.
// REGISTER DISCIPLINE (the binding constraint, rounds 1-7): each layer is
// split into two gate-passes so no phase exceeds 4 accumulators (64 AGPR)
// + <=4 weight streams. {r,z} parked as f16 (16 regs) between passes; h_new
// deferred in hv (32 regs) and written after a barrier (h single-buffered).
// h element (tile,row,k) at LDS byte: tl*32768 + row*1024 + ((2k) ^ ((row&7)<<4))
__global__ __launch_bounds__(512, 2) void gru_fused(
    const float* __restrict__ z,
    const float* __restrict__ w_ih1,   // [1536][3] fp32
    const float* __restrict__ fc_w,    // [3][512]  fp32
    const float* __restrict__ fc_b,    // [3]
    const f16*  __restrict__ Wp,       // packed Whh1 | Wih2 | Whh2
    const float* __restrict__ Bb,      // bias1[2048] | bias2[2048]
    float* __restrict__ out)           // [B][100][3] fp32
{
  __shared__ f16   h1s[2 * 32 * HID];   // 64 KB  [tile][row][col]
  __shared__ f16   h2s[2 * 32 * HID];   // 64 KB
  __shared__ float fcwT[3 * HID];       // 6 KB   pos(k) = (k&7)*64 + (k>>3)
  __shared__ float xsf[64 * 4];         // 1 KB   fp32 x state per global row

  const int tid  = threadIdx.x;
  const int lane = tid & 63;
  const int wv   = tid >> 6;            // 0..7
  const int b0   = blockIdx.x * 64;

  {
    f16x8 z8 = {0, 0, 0, 0, 0, 0, 0, 0};
    for (int i = tid; i < 2 * 32 * HID / 8; i += 512) {
      ((f16x8*)h1s)[i] = z8;
      ((f16x8*)h2s)[i] = z8;
    }
    if (tid < HID) {
      const int pos = ((tid & 7) << 6) + (tid >> 3);
      fcwT[pos]        = fc_w[tid];
      fcwT[512 + pos]  = fc_w[512 + tid];
      fcwT[1024 + pos] = fc_w[1024 + tid];
    }
  }
  __syncthreads();
  if (tid < 64 * 3) {
    const int rr = tid / 3, oo = tid - rr * 3;
    float v = z[(size_t)(b0 + rr) * 6 + 3 + oo];
    xsf[rr * 4 + oo] = v;
    out[(size_t)(b0 + rr) * 300 + oo] = v;     // t = 0 output
  }
  __syncthreads();

  const int colid = lane & 31;
  const int khalf = lane >> 5;
  const int klo   = khalf << 4;
  const int patA  = (colid & 7) << 4;
  const int rbase = colid * 1024;
  const int jw    = wv << 6;            // wave owns cols [jw, jw+64)

  const f16* W1  = Wp;
  const f16* Wi2 = Wp + WMAT;
  const f16* Wh2 = Wp + 2 * WMAT;

  // per-chunk constants (constant over t)
  float b1r[2], b1z[2], b1ni[2], b1nh[2], b2r[2], b2z[2], b2ni[2], b2nh[2];
  float wr0[2], wr1[2], wr2[2], wz0[2], wz1[2], wz2[2], wn0[2], wn1[2], wn2[2];
#pragma unroll
  for (int c = 0; c < 2; ++c) {
    const int j = jw + (c << 5) + colid;
    b1r[c]  = Bb[j];         b1z[c]  = Bb[512 + j];
    b1ni[c] = Bb[1024 + j];  b1nh[c] = Bb[1536 + j];
    b2r[c]  = Bb[2048 + j];         b2z[c]  = Bb[2048 + 512 + j];
    b2ni[c] = Bb[2048 + 1024 + j];  b2nh[c] = Bb[2048 + 1536 + j];
    wr0[c] = w_ih1[j * 3];             wr1[c] = w_ih1[j * 3 + 1];             wr2[c] = w_ih1[j * 3 + 2];
    wz0[c] = w_ih1[(512 + j) * 3];     wz1[c] = w_ih1[(512 + j) * 3 + 1];     wz2[c] = w_ih1[(512 + j) * 3 + 2];
    wn0[c] = w_ih1[(1024 + j) * 3];    wn1[c] = w_ih1[(1024 + j) * 3 + 1];    wn2[c] = w_ih1[(1024 + j) * 3 + 2];
  }
  const float fb0 = fc_b[0], fb1 = fc_b[1], fb2 = fc_b[2];

  for (int t = 1; t < NSTEP; ++t) {
    f16x8 hv[2][2][2];   // deferred h_new: [chunk][tile][half]  (32 VGPR)

    // ======== Layer 1: per chunk, pass {r,z} (4 accs) then pass {n} (2 accs) ========
#pragma unroll
    for (int c = 0; c < 2; ++c) {
      const int ct = (wv << 1) + c;
      const int jxc = 2 * (jw + (c << 5) + colid);
      f16x8 rv[2][2], zv[2][2];   // parked gates (16 VGPR)

      {  // ---- pass 1: r,z ----
        f32x16 aR0 = zero16(), aR1 = zero16();
        f32x16 aZ0 = zero16(), aZ1 = zero16();
        const f16* Br = W1 + (size_t)ct * 16384 + lane * 8;
        const f16* Bz = W1 + (size_t)(16 + ct) * 16384 + lane * 8;
#pragma unroll 2
        for (int kt = 0; kt < 32; ++kt) {
          const int koff = ((kt << 5) | klo) ^ patA;
          f16x8 a0 = *(const f16x8*)((const char*)h1s + rbase + koff);
          f16x8 a1 = *(const f16x8*)((const char*)h1s + 32768 + rbase + koff);
          f16x8 br = *(const f16x8*)(Br + kt * 512);
          f16x8 bz = *(const f16x8*)(Bz + kt * 512);
          aR0 = mfma16(a0, br, aR0);  aR1 = mfma16(a1, br, aR1);
          aZ0 = mfma16(a0, bz, aZ0);  aZ1 = mfma16(a1, bz, aZ1);
        }
#pragma unroll
        for (int tl = 0; tl < 2; ++tl) {
          const f32x16 aR = tl ? aR1 : aR0;
          const f32x16 aZ = tl ? aZ1 : aZ0;
#pragma unroll
          for (int qq = 0; qq < 16; ++qq) {
            const int row = (qq & 3) + ((qq >> 2) << 3) + (khalf << 2);
            const float4 xv = *(const float4*)(xsf + ((tl << 5) + row) * 4);
            const float gir = fmaf(xv.x, wr0[c], fmaf(xv.y, wr1[c], xv.z * wr2[c]));
            const float giz = fmaf(xv.x, wz0[c], fmaf(xv.y, wz1[c], xv.z * wz2[c]));
            rv[tl][qq >> 3][qq & 7] = (f16)sigmoid_f(aR[qq] + gir + b1r[c]);
            zv[tl][qq >> 3][qq & 7] = (f16)sigmoid_f(aZ[qq] + giz + b1z[c]);
          }
        }
      }
      {  // ---- pass 2: n + h_new ----
        f32x16 aN0 = zero16(), aN1 = zero16();
        const f16* Bn = W1 + (size_t)(32 + ct) * 16384 + lane * 8;
#pragma unroll 2
        for (int kt = 0; kt < 32; ++kt) {
          const int koff = ((kt << 5) | klo) ^ patA;
          f16x8 a0 = *(const f16x8*)((const char*)h1s + rbase + koff);
          f16x8 a1 = *(const f16x8*)((const char*)h1s + 32768 + rbase + koff);
          f16x8 bn = *(const f16x8*)(Bn + kt * 512);
          aN0 = mfma16(a0, bn, aN0);  aN1 = mfma16(a1, bn, aN1);
        }
#pragma unroll
        for (int tl = 0; tl < 2; ++tl) {
          const f32x16 aN = tl ? aN1 : aN0;
#pragma unroll
          for (int qq = 0; qq < 16; ++qq) {
            const int row = (qq & 3) + ((qq >> 2) << 3) + (khalf << 2);
            const float4 xv = *(const float4*)(xsf + ((tl << 5) + row) * 4);
            const float gin = fmaf(xv.x, wn0[c], fmaf(xv.y, wn1[c], xv.z * wn2[c]));
            float r  = (float)rv[tl][qq >> 3][qq & 7];
            float zt = (float)zv[tl][qq >> 3][qq & 7];
            float n  = tanh_f(gin + b1ni[c] + r * (aN[qq] + b1nh[c]));
            float hold = (float)*(const f16*)((const char*)h1s + tl * 32768 + row * 1024 + (jxc ^ ((row & 7) << 4)));
            hv[c][tl][qq >> 3][qq & 7] = (f16)((1.0f - zt) * n + zt * hold);
          }
        }
      }
    }
    __syncthreads();
#pragma unroll
    for (int c = 0; c < 2; ++c) {
      const int jxc = 2 * (jw + (c << 5) + colid);
#pragma unroll
      for (int tl = 0; tl < 2; ++tl)
#pragma unroll
        for (int qq = 0; qq < 16; ++qq) {
          const int row = (qq & 3) + ((qq >> 2) << 3) + (khalf << 2);
          *(f16*)((char*)h1s + tl * 32768 + row * 1024 + (jxc ^ ((row & 7) << 4))) = hv[c][tl][qq >> 3][qq & 7];
        }
    }
    __syncthreads();

    // ======== Layer 2: per chunk, pass {r,z} (4 accs, 4 streams) then {n} (4 accs, 2 streams) ========
#pragma unroll
    for (int c = 0; c < 2; ++c) {
      const int ct = (wv << 1) + c;
      const int jxc = 2 * (jw + (c << 5) + colid);
      f16x8 rv[2][2], zv[2][2];

      {  // ---- pass 1: r,z ----
        f32x16 aR0 = zero16(), aR1 = zero16();
        f32x16 aZ0 = zero16(), aZ1 = zero16();
        const f16* Bir = Wi2 + (size_t)ct * 16384 + lane * 8;
        const f16* Biz = Wi2 + (size_t)(16 + ct) * 16384 + lane * 8;
        const f16* Bhr = Wh2 + (size_t)ct * 16384 + lane * 8;
        const f16* Bhz = Wh2 + (size_t)(16 + ct) * 16384 + lane * 8;
#pragma unroll 2
        for (int kt = 0; kt < 32; ++kt) {
          const int koff = ((kt << 5) | klo) ^ patA;
          f16x8 a10 = *(const f16x8*)((const char*)h1s + rbase + koff);
          f16x8 a11 = *(const f16x8*)((const char*)h1s + 32768 + rbase + koff);
          f16x8 a20 = *(const f16x8*)((const char*)h2s + rbase + koff);
          f16x8 a21 = *(const f16x8*)((const char*)h2s + 32768 + rbase + koff);
          aR0 = mfma16(a10, *(const f16x8*)(Bir + kt * 512), aR0);
          aR0 = mfma16(a20, *(const f16x8*)(Bhr + kt * 512), aR0);
          aR1 = mfma16(a11, *(const f16x8*)(Bir + kt * 512), aR1);
          aR1 = mfma16(a21, *(const f16x8*)(Bhr + kt * 512), aR1);
          aZ0 = mfma16(a10, *(const f16x8*)(Biz + kt * 512), aZ0);
          aZ0 = mfma16(a20, *(const f16x8*)(Bhz + kt * 512), aZ0);
          aZ1 = mfma16(a11, *(const f16x8*)(Biz + kt * 512), aZ1);
          aZ1 = mfma16(a21, *(const f16x8*)(Bhz + kt * 512), aZ1);
        }
#pragma unroll
        for (int tl = 0; tl < 2; ++tl) {
          const f32x16 aR = tl ? aR1 : aR0;
          const f32x16 aZ = tl ? aZ1 : aZ0;
#pragma unroll
          for (int qq = 0; qq < 16; ++qq) {
            rv[tl][qq >> 3][qq & 7] = (f16)sigmoid_f(aR[qq] + b2r[c]);
            zv[tl][qq >> 3][qq & 7] = (f16)sigmoid_f(aZ[qq] + b2z[c]);
          }
        }
      }
      {  // ---- pass 2: n + h_new ----
        f32x16 aI0 = zero16(), aI1 = zero16();
        f32x16 aH0 = zero16(), aH1 = zero16();
        const f16* Bin = Wi2 + (size_t)(32 + ct) * 16384 + lane * 8;
        const f16* Bhn = Wh2 + (size_t)(32 + ct) * 16384 + lane * 8;
#pragma unroll 2
        for (int kt = 0; kt < 32; ++kt) {
          const int koff = ((kt << 5) | klo) ^ patA;
          f16x8 a10 = *(const f16x8*)((const char*)h1s + rbase + koff);
          f16x8 a11 = *(const f16x8*)((const char*)h1s + 32768 + rbase + koff);
          f16x8 a20 = *(const f16x8*)((const char*)h2s + rbase + koff);
          f16x8 a21 = *(const f16x8*)((const char*)h2s + 32768 + rbase + koff);
          aI0 = mfma16(a10, *(const f16x8*)(Bin + kt * 512), aI0);
          aI1 = mfma16(a11, *(const f16x8*)(Bin + kt * 512), aI1);
          aH0 = mfma16(a20, *(const f16x8*)(Bhn + kt * 512), aH0);
          aH1 = mfma16(a21, *(const f16x8*)(Bhn + kt * 512), aH1);
        }
#pragma unroll
        for (int tl = 0; tl < 2; ++tl) {
          const f32x16 aI = tl ? aI1 : aI0;
          const f32x16 aH = tl ? aH1 : aH0;
#pragma unroll
          for (int qq = 0; qq < 16; ++qq) {
            const int row = (qq & 3) + ((qq >> 2) << 3) + (khalf << 2);
            float r  = (float)rv[tl][qq >> 3][qq & 7];
            float zt = (float)zv[tl][qq >> 3][qq & 7];
            float n  = tanh_f(aI[qq] + b2ni[c] + r * (aH[qq] + b2nh[c]));
            float hold = (float)*(const f16*)((const char*)h2s + tl * 32768 + row * 1024 + (jxc ^ ((row & 7) << 4)));
            hv[c][tl][qq >> 3][qq & 7] = (f16)((1.0f - zt) * n + zt * hold);
          }
        }
      }
    }
    __syncthreads();
#pragma unroll
    for (int c = 0; c < 2; ++c) {
      const int jxc = 2 * (jw + (c << 5) + colid);
#pragma unroll
      for (int tl = 0; tl < 2; ++tl)
#pragma unroll
        for (int qq = 0; qq < 16; ++qq) {
          const int row = (qq & 3) + ((qq >> 2) << 3) + (khalf << 2);
          *(f16*)((char*)h2s + tl * 32768 + row * 1024 + (jxc ^ ((row & 7) << 4))) = hv[c][tl][qq >> 3][qq & 7];
        }
    }
    __syncthreads();

    // ================= FC head: 8 waves x 8 rows, 8-lane shuffle reduce =================
    {
      const int rowg = (wv << 3) + (lane >> 3);   // global row 0..63
      const int tl   = rowg >> 5;
      const int rit  = rowg & 31;
      const int sl   = lane & 7;                  // k-slice of 64
      const char* hb = (const char*)h2s + tl * 32768 + rit * 1024;
      const int pat = (rit & 7) << 4;
      float p0 = 0.f, p1 = 0.f, p2 = 0.f;
#pragma unroll
      for (int j = 0; j < 8; ++j) {
        f16x8 hh = *(const f16x8*)(hb + (((sl << 7) | (j << 4)) ^ pat));
#pragma unroll
        for (int i = 0; i < 8; ++i) {
          const float hf = (float)hh[i];
          const int pos = (i << 6) + (sl << 3) + j;
          p0 = fmaf(hf, fcwT[pos], p0);
          p1 = fmaf(hf, fcwT[512 + pos], p1);
          p2 = fmaf(hf, fcwT[1024 + pos], p2);
        }
      }
#pragma unroll
      for (int m = 1; m < 8; m <<= 1) {
        p0 += __shfl_xor(p0, m, 64);
        p1 += __shfl_xor(p1, m, 64);
        p2 += __shfl_xor(p2, m, 64);
      }
      if (sl == 0) {
        float x0 = xsf[(rowg << 2) + 0] + 0.1f * tanh_f(p0 + fb0);
        float x1 = xsf[(rowg << 2) + 1] + 0.1f * tanh_f(p1 + fb1);
        float x2 = xsf[(rowg << 2) + 2] + 0.1f * tanh_f(p2 + fb2);
        xsf[(rowg << 2) + 0] = x0;
        xsf[(rowg << 2) + 1] = x1;
        xsf[(rowg << 2) + 2] = x2;
        float* op = out + (size_t)(b0 + rowg) * 300 + (size_t)t * 3;
        op[0] = x0; op[1] = x1; op[2] = x2;
      }
    }
    __syncthreads();
  }
}

extern "C" void kernel_launch(void* const* d_in, const int* in_sizes, int n_in,
                              void* d_out, int out_size, void* d_ws, size_t ws_size,
                              hipStream_t stream) {
  const float* z     = (const float*)d_in[0];
  const float* w_ih1 = (const float*)d_in[1];
  const float* w_hh1 = (const float*)d_in[2];
  const float* b_ih1 = (const float*)d_in[3];
  const float* b_hh1 = (const float*)d_in[4];
  const float* w_ih2 = (const float*)d_in[5];
  const float* w_hh2 = (const float*)d_in[6];
  const float* b_ih2 = (const float*)d_in[7];
  const float* b_hh2 = (const float*)d_in[8];
  const float* fc_w  = (const float*)d_in[9];
  const float* fc_b  = (const float*)d_in[10];
  float* out = (float*)d_out;

  f16*   Wp = (f16*)d_ws;                                          // 3 * 1.5 MB packed fp16
  float* Bb = (float*)((char*)d_ws + (size_t)3 * WMAT * 2);

  const int nbatch = in_sizes[0] / 6;

  pack_weights<<<384, 256, 0, stream>>>(w_hh1, Wp);
  pack_weights<<<384, 256, 0, stream>>>(w_ih2, Wp + WMAT);
  pack_weights<<<384, 256, 0, stream>>>(w_hh2, Wp + 2 * WMAT);
  pack_bias<<<8, 256, 0, stream>>>(b_ih1, b_hh1, Bb);
  pack_bias<<<8, 256, 0, stream>>>(b_ih2, b_hh2, Bb + 2048);

  gru_fused<<<nbatch / 64, 512, 0, stream>>>(z, w_ih1, fc_w, fc_b, Wp, Bb, out);
}

// Round 9
// 22565.321 us; speedup vs baseline: 1.7173x; 1.7173x over previous
//
#include <hip/hip_runtime.h>

typedef _Float16 f16;
typedef _Float16 f16x8 __attribute__((ext_vector_type(8)));
typedef float f32x16 __attribute__((ext_vector_type(16)));

#define HID   512
#define NSTEP 100
#define WMAT  786432      // halfs per packed weight matrix (1536*512)

__device__ __forceinline__ float sigmoid_f(float x) {
  return 1.0f / (1.0f + __expf(-x));
}
__device__ __forceinline__ float tanh_f(float x) {
  float e = __expf(2.0f * x);
  return 1.0f - 2.0f / (e + 1.0f);
}
__device__ __forceinline__ f32x16 mfma16(f16x8 a, f16x8 b, f32x16 c) {
  return __builtin_amdgcn_mfma_f32_32x32x16_f16(a, b, c, 0, 0, 0);
}
__device__ __forceinline__ f32x16 zero16() {
  f32x16 z;
#pragma unroll
  for (int i = 0; i < 16; ++i) z[i] = 0.f;
  return z;
}

// ---- weight pack: fp32 [1536][512] row-major -> B-fragment-packed fp16 ----
// layout [ct(48)][kt(32)][lane(64)][i(8)]:
//   gate = ct*32 + (lane&31), k = kt*16 + (lane>>5)*8 + i
__global__ void pack_weights(const float* __restrict__ W, f16* __restrict__ out) {
  int t = blockIdx.x * 256 + threadIdx.x;
  if (t >= 48 * 32 * 64) return;
  int lane = t & 63;
  int kt   = (t >> 6) & 31;
  int ct   = t >> 11;
  int gate = ct * 32 + (lane & 31);
  int k0   = kt * 16 + (lane >> 5) * 8;
  const float* src = W + gate * HID + k0;
  f16x8 v;
#pragma unroll
  for (int i = 0; i < 8; ++i) v[i] = (f16)src[i];
  *(f16x8*)(out + (size_t)t * 8) = v;
}

// w_ih1 + combined bias -> K=16 B tiles: slots [w0,w1,w2, bi+bh, 0...]
// (used for r,z gates only; n-gate tiles packed but unused)
__global__ void pack_wx(const float* __restrict__ W, const float* __restrict__ bi,
                        const float* __restrict__ bh, f16* __restrict__ out) {
  int t = blockIdx.x * 256 + threadIdx.x;
  if (t >= 48 * 64) return;
  int lane = t & 63;
  int ct   = t >> 6;
  int col  = ct * 32 + (lane & 31);
  int k0   = (lane >> 5) * 8;
  f16x8 v;
#pragma unroll
  for (int i = 0; i < 8; ++i) {
    int k = k0 + i;
    float x = 0.f;
    if (k < 3)       x = W[col * 3 + k];
    else if (k == 3) x = bi[col] + bh[col];
    v[i] = (f16)x;
  }
  *(f16x8*)(out + (size_t)t * 8) = v;
}

// combined biases: [0..1023]=bi+bh (r,z), [1024..1535]=bi_n, [1536..2047]=bh_n
__global__ void pack_bias(const float* __restrict__ bi, const float* __restrict__ bh,
                          float* __restrict__ out) {
  int j = blockIdx.x * 256 + threadIdx.x;
  if (j < 1024)      out[j] = bi[j] + bh[j];
  else if (j < 1536) out[j] = bi[j];
  else if (j < 2048) out[j] = bh[j - 512];
}

// Persistent per-block GRU, BT=64 (two 32-row tiles share every B-fragment),
// 8 waves x 64 cols, grid=256 (one generation).
// REGISTER DISCIPLINE: one gate per pass; cross-phase state is ONLY two f16x8
// park arrays g1,g2 (64 VGPR), reused in place (r -> rH -> n). No deferred
// h-write arrays: the barrier separates all h_old READS (kt loops) from
// in-place h_new WRITES (epilogue reads own h_old element, then overwrites).
// h element (tile,row,k) at LDS byte: tl*32768 + row*1024 + ((2k) ^ ((row&7)<<4))
__global__ __launch_bounds__(512, 2) void gru_fused(
    const float* __restrict__ z,
    const float* __restrict__ w_ih1,   // [1536][3] fp32 (n-gate scalars)
    const float* __restrict__ fc_w,    // [3][512]  fp32
    const float* __restrict__ fc_b,    // [3]
    const f16*  __restrict__ Wp,       // packed Whh1 | Wih2 | Whh2
    const f16*  __restrict__ Wx,       // packed w_ih1 r,z tiles (K-ext with bias)
    const float* __restrict__ Bb,      // bias1[2048] | bias2[2048]
    float* __restrict__ out)           // [B][100][3] fp32
{
  __shared__ f16   h1s[64 * HID];       // 64 KB  [tile(2)][row(32)][col(512)]
  __shared__ f16   h2s[64 * HID];       // 64 KB
  __shared__ f16   xs16[64 * 16];       // 2 KB   K-ext A-tile: [x0,x1,x2,1,0..]
  __shared__ float fcwT[3 * HID];       // 6 KB   pos(k) = (k&7)*64 + (k>>3)
  __shared__ float xsf[64 * 4];         // 1 KB   fp32 x state

  const int tid  = threadIdx.x;
  const int lane = tid & 63;
  const int wv   = tid >> 6;            // 0..7
  const int b0   = blockIdx.x * 64;

  {
    f16x8 z8 = {0, 0, 0, 0, 0, 0, 0, 0};
    for (int i = tid; i < 64 * HID / 8; i += 512) {
      ((f16x8*)h1s)[i] = z8;
      ((f16x8*)h2s)[i] = z8;
    }
    if (tid < 64) {
#pragma unroll
      for (int k = 0; k < 16; ++k) xs16[tid * 16 + k] = (f16)((k == 3) ? 1.f : 0.f);
    }
    if (tid < HID) {
      const int pos = ((tid & 7) << 6) + (tid >> 3);
      fcwT[pos]        = fc_w[tid];
      fcwT[512 + pos]  = fc_w[512 + tid];
      fcwT[1024 + pos] = fc_w[1024 + tid];
    }
  }
  __syncthreads();
  if (tid < 64 * 3) {
    const int rr = tid / 3, oo = tid - rr * 3;
    float v = z[(size_t)(b0 + rr) * 6 + 3 + oo];
    xsf[rr * 4 + oo] = v;
    xs16[rr * 16 + oo] = (f16)v;
    out[(size_t)(b0 + rr) * 300 + oo] = v;     // t = 0 output
  }
  __syncthreads();

  const int colid = lane & 31;
  const int khalf = lane >> 5;
  const int klo   = khalf << 4;
  const int patA  = (colid & 7) << 4;
  const int rbase = colid * 1024;
  const int jw    = wv << 6;            // wave owns cols [jw, jw+64)
  const int ct0   = wv << 1;            // col-chunk tile indices
  const int ct1   = ct0 + 1;

  const f16* Wi2 = Wp + WMAT;
  const f16* Wh2 = Wp + 2 * WMAT;

  // scalar constants (constant over t)
  float b1ni[2], b1nh[2], b2r[2], b2z[2], b2ni[2], b2nh[2];
  float wn0[2], wn1[2], wn2[2];
#pragma unroll
  for (int c = 0; c < 2; ++c) {
    const int j = jw + (c << 5) + colid;
    b1ni[c] = Bb[1024 + j];  b1nh[c] = Bb[1536 + j];
    b2r[c]  = Bb[2048 + j];         b2z[c]  = Bb[2048 + 512 + j];
    b2ni[c] = Bb[2048 + 1024 + j];  b2nh[c] = Bb[2048 + 1536 + j];
    wn0[c] = w_ih1[(1024 + j) * 3];
    wn1[c] = w_ih1[(1024 + j) * 3 + 1];
    wn2[c] = w_ih1[(1024 + j) * 3 + 2];
  }
  const float fb0 = fc_b[0], fb1 = fc_b[1], fb2 = fc_b[2];
  const int xoff0 = colid * 32 + klo;        // xs16 byte offsets
  const int xoff1 = (32 + colid) * 32 + klo;

  for (int t = 1; t < NSTEP; ++t) {
    f16x8 g1[2][2][2], g2[2][2][2];   // the ONLY cross-phase state (64 VGPR)

    // ========== L1 pass r: acc = Whh1_r·h1 + [wih1_r|b]·[x|1]  -> g1 = sigma ==========
    {
      f32x16 a00 = zero16(), a01 = zero16(), a10 = zero16(), a11 = zero16();
      const f16* B0 = Wp + (size_t)ct0 * 16384 + lane * 8;
      const f16* B1 = Wp + (size_t)ct1 * 16384 + lane * 8;
#pragma unroll 2
      for (int kt = 0; kt < 32; ++kt) {
        const int koff = ((kt << 5) | klo) ^ patA;
        f16x8 a0 = *(const f16x8*)((const char*)h1s + rbase + koff);
        f16x8 a1 = *(const f16x8*)((const char*)h1s + 32768 + rbase + koff);
        f16x8 b0 = *(const f16x8*)(B0 + kt * 512);
        f16x8 b1 = *(const f16x8*)(B1 + kt * 512);
        a00 = mfma16(a0, b0, a00);  a01 = mfma16(a1, b0, a01);
        a10 = mfma16(a0, b1, a10);  a11 = mfma16(a1, b1, a11);
      }
      {  // K-extension: x + bias
        f16x8 ax0 = *(const f16x8*)((const char*)xs16 + xoff0);
        f16x8 ax1 = *(const f16x8*)((const char*)xs16 + xoff1);
        f16x8 bx0 = *(const f16x8*)(Wx + (size_t)ct0 * 512 + lane * 8);
        f16x8 bx1 = *(const f16x8*)(Wx + (size_t)ct1 * 512 + lane * 8);
        a00 = mfma16(ax0, bx0, a00);  a01 = mfma16(ax1, bx0, a01);
        a10 = mfma16(ax0, bx1, a10);  a11 = mfma16(ax1, bx1, a11);
      }
#pragma unroll
      for (int q = 0; q < 16; ++q) {
        g1[0][0][q >> 3][q & 7] = (f16)sigmoid_f(a00[q]);
        g1[0][1][q >> 3][q & 7] = (f16)sigmoid_f(a01[q]);
        g1[1][0][q >> 3][q & 7] = (f16)sigmoid_f(a10[q]);
        g1[1][1][q >> 3][q & 7] = (f16)sigmoid_f(a11[q]);
      }
    }
    // ========== L1 pass z -> g2 ==========
    {
      f32x16 a00 = zero16(), a01 = zero16(), a10 = zero16(), a11 = zero16();
      const f16* B0 = Wp + (size_t)(16 + ct0) * 16384 + lane * 8;
      const f16* B1 = Wp + (size_t)(16 + ct1) * 16384 + lane * 8;
#pragma unroll 2
      for (int kt = 0; kt < 32; ++kt) {
        const int koff = ((kt << 5) | klo) ^ patA;
        f16x8 a0 = *(const f16x8*)((const char*)h1s + rbase + koff);
        f16x8 a1 = *(const f16x8*)((const char*)h1s + 32768 + rbase + koff);
        f16x8 b0 = *(const f16x8*)(B0 + kt * 512);
        f16x8 b1 = *(const f16x8*)(B1 + kt * 512);
        a00 = mfma16(a0, b0, a00);  a01 = mfma16(a1, b0, a01);
        a10 = mfma16(a0, b1, a10);  a11 = mfma16(a1, b1, a11);
      }
      {
        f16x8 ax0 = *(const f16x8*)((const char*)xs16 + xoff0);
        f16x8 ax1 = *(const f16x8*)((const char*)xs16 + xoff1);
        f16x8 bx0 = *(const f16x8*)(Wx + (size_t)(16 + ct0) * 512 + lane * 8);
        f16x8 bx1 = *(const f16x8*)(Wx + (size_t)(16 + ct1) * 512 + lane * 8);
        a00 = mfma16(ax0, bx0, a00);  a01 = mfma16(ax1, bx0, a01);
        a10 = mfma16(ax0, bx1, a10);  a11 = mfma16(ax1, bx1, a11);
      }
#pragma unroll
      for (int q = 0; q < 16; ++q) {
        g2[0][0][q >> 3][q & 7] = (f16)sigmoid_f(a00[q]);
        g2[0][1][q >> 3][q & 7] = (f16)sigmoid_f(a01[q]);
        g2[1][0][q >> 3][q & 7] = (f16)sigmoid_f(a10[q]);
        g2[1][1][q >> 3][q & 7] = (f16)sigmoid_f(a11[q]);
      }
    }
    // ========== L1 pass n (sequential chunks): g1 <- n = tanh(gin_x + r*(gh+b)) ==========
#pragma unroll
    for (int c = 0; c < 2; ++c) {
      f32x16 an0 = zero16(), an1 = zero16();
      const f16* Bn = Wp + (size_t)(32 + ct0 + c) * 16384 + lane * 8;
#pragma unroll 2
      for (int kt = 0; kt < 32; ++kt) {
        const int koff = ((kt << 5) | klo) ^ patA;
        f16x8 a0 = *(const f16x8*)((const char*)h1s + rbase + koff);
        f16x8 a1 = *(const f16x8*)((const char*)h1s + 32768 + rbase + koff);
        f16x8 bn = *(const f16x8*)(Bn + kt * 512);
        an0 = mfma16(a0, bn, an0);  an1 = mfma16(a1, bn, an1);
      }
#pragma unroll
      for (int tl = 0; tl < 2; ++tl) {
        const f32x16 an = tl ? an1 : an0;
#pragma unroll
        for (int q = 0; q < 16; ++q) {
          const int row = (q & 3) + ((q >> 2) << 3) + (khalf << 2);
          const float4 xv = *(const float4*)(xsf + ((tl << 5) + row) * 4);
          const float gin = fmaf(xv.x, wn0[c], fmaf(xv.y, wn1[c], xv.z * wn2[c]));
          float r = (float)g1[c][tl][q >> 3][q & 7];
          g1[c][tl][q >> 3][q & 7] = (f16)tanh_f(gin + b1ni[c] + r * (an[q] + b1nh[c]));
        }
      }
    }
    __syncthreads();   // all h1_old reads done
    // ---- epi1: in-place h1 update from g1(=n), g2(=z) ----
#pragma unroll
    for (int c = 0; c < 2; ++c) {
      const int jxc = 2 * (jw + (c << 5) + colid);
#pragma unroll
      for (int tl = 0; tl < 2; ++tl)
#pragma unroll
        for (int q = 0; q < 16; ++q) {
          const int row = (q & 3) + ((q >> 2) << 3) + (khalf << 2);
          f16* hp = (f16*)((char*)h1s + tl * 32768 + row * 1024 + (jxc ^ ((row & 7) << 4)));
          float zt = (float)g2[c][tl][q >> 3][q & 7];
          float n  = (float)g1[c][tl][q >> 3][q & 7];
          float hold = (float)*hp;
          *hp = (f16)((1.0f - zt) * n + zt * hold);
        }
    }
    __syncthreads();   // h1_new visible

    // ========== L2 pass r: acc = Wi2_r·h1 + Wh2_r·h2 -> g1 = sigma ==========
    {
      f32x16 a00 = zero16(), a01 = zero16(), a10 = zero16(), a11 = zero16();
      const f16* Bi0 = Wi2 + (size_t)ct0 * 16384 + lane * 8;
      const f16* Bi1 = Wi2 + (size_t)ct1 * 16384 + lane * 8;
      const f16* Bh0 = Wh2 + (size_t)ct0 * 16384 + lane * 8;
      const f16* Bh1 = Wh2 + (size_t)ct1 * 16384 + lane * 8;
#pragma unroll 2
      for (int kt = 0; kt < 32; ++kt) {
        const int koff = ((kt << 5) | klo) ^ patA;
        f16x8 x0 = *(const f16x8*)((const char*)h1s + rbase + koff);
        f16x8 x1 = *(const f16x8*)((const char*)h1s + 32768 + rbase + koff);
        f16x8 y0 = *(const f16x8*)((const char*)h2s + rbase + koff);
        f16x8 y1 = *(const f16x8*)((const char*)h2s + 32768 + rbase + koff);
        f16x8 bi0 = *(const f16x8*)(Bi0 + kt * 512);
        f16x8 bi1 = *(const f16x8*)(Bi1 + kt * 512);
        f16x8 bh0 = *(const f16x8*)(Bh0 + kt * 512);
        f16x8 bh1 = *(const f16x8*)(Bh1 + kt * 512);
        a00 = mfma16(x0, bi0, a00);  a00 = mfma16(y0, bh0, a00);
        a01 = mfma16(x1, bi0, a01);  a01 = mfma16(y1, bh0, a01);
        a10 = mfma16(x0, bi1, a10);  a10 = mfma16(y0, bh1, a10);
        a11 = mfma16(x1, bi1, a11);  a11 = mfma16(y1, bh1, a11);
      }
#pragma unroll
      for (int q = 0; q < 16; ++q) {
        g1[0][0][q >> 3][q & 7] = (f16)sigmoid_f(a00[q] + b2r[0]);
        g1[0][1][q >> 3][q & 7] = (f16)sigmoid_f(a01[q] + b2r[0]);
        g1[1][0][q >> 3][q & 7] = (f16)sigmoid_f(a10[q] + b2r[1]);
        g1[1][1][q >> 3][q & 7] = (f16)sigmoid_f(a11[q] + b2r[1]);
      }
    }
    // ========== L2 pass z -> g2 ==========
    {
      f32x16 a00 = zero16(), a01 = zero16(), a10 = zero16(), a11 = zero16();
      const f16* Bi0 = Wi2 + (size_t)(16 + ct0) * 16384 + lane * 8;
      const f16* Bi1 = Wi2 + (size_t)(16 + ct1) * 16384 + lane * 8;
      const f16* Bh0 = Wh2 + (size_t)(16 + ct0) * 16384 + lane * 8;
      const f16* Bh1 = Wh2 + (size_t)(16 + ct1) * 16384 + lane * 8;
#pragma unroll 2
      for (int kt = 0; kt < 32; ++kt) {
        const int koff = ((kt << 5) | klo) ^ patA;
        f16x8 x0 = *(const f16x8*)((const char*)h1s + rbase + koff);
        f16x8 x1 = *(const f16x8*)((const char*)h1s + 32768 + rbase + koff);
        f16x8 y0 = *(const f16x8*)((const char*)h2s + rbase + koff);
        f16x8 y1 = *(const f16x8*)((const char*)h2s + 32768 + rbase + koff);
        f16x8 bi0 = *(const f16x8*)(Bi0 + kt * 512);
        f16x8 bi1 = *(const f16x8*)(Bi1 + kt * 512);
        f16x8 bh0 = *(const f16x8*)(Bh0 + kt * 512);
        f16x8 bh1 = *(const f16x8*)(Bh1 + kt * 512);
        a00 = mfma16(x0, bi0, a00);  a00 = mfma16(y0, bh0, a00);
        a01 = mfma16(x1, bi0, a01);  a01 = mfma16(y1, bh0, a01);
        a10 = mfma16(x0, bi1, a10);  a10 = mfma16(y0, bh1, a10);
        a11 = mfma16(x1, bi1, a11);  a11 = mfma16(y1, bh1, a11);
      }
#pragma unroll
      for (int q = 0; q < 16; ++q) {
        g2[0][0][q >> 3][q & 7] = (f16)sigmoid_f(a00[q] + b2z[0]);
        g2[0][1][q >> 3][q & 7] = (f16)sigmoid_f(a01[q] + b2z[0]);
        g2[1][0][q >> 3][q & 7] = (f16)sigmoid_f(a10[q] + b2z[1]);
        g2[1][1][q >> 3][q & 7] = (f16)sigmoid_f(a11[q] + b2z[1]);
      }
    }
    // ========== L2 pass nH (sequential): g1 <- r*(gh_n + b2nh) ==========
#pragma unroll
    for (int c = 0; c < 2; ++c) {
      f32x16 an0 = zero16(), an1 = zero16();
      const f16* Bn = Wh2 + (size_t)(32 + ct0 + c) * 16384 + lane * 8;
#pragma unroll 2
      for (int kt = 0; kt < 32; ++kt) {
        const int koff = ((kt << 5) | klo) ^ patA;
        f16x8 y0 = *(const f16x8*)((const char*)h2s + rbase + koff);
        f16x8 y1 = *(const f16x8*)((const char*)h2s + 32768 + rbase + koff);
        f16x8 bn = *(const f16x8*)(Bn + kt * 512);
        an0 = mfma16(y0, bn, an0);  an1 = mfma16(y1, bn, an1);
      }
#pragma unroll
      for (int tl = 0; tl < 2; ++tl) {
        const f32x16 an = tl ? an1 : an0;
#pragma unroll
        for (int q = 0; q < 16; ++q) {
          float r = (float)g1[c][tl][q >> 3][q & 7];
          g1[c][tl][q >> 3][q & 7] = (f16)(r * (an[q] + b2nh[c]));
        }
      }
    }
    // ========== L2 pass nI (sequential): g1 <- n = tanh(gi_n + b2ni + g1) ==========
#pragma unroll
    for (int c = 0; c < 2; ++c) {
      f32x16 an0 = zero16(), an1 = zero16();
      const f16* Bn = Wi2 + (size_t)(32 + ct0 + c) * 16384 + lane * 8;
#pragma unroll 2
      for (int kt = 0; kt < 32; ++kt) {
        const int koff = ((kt << 5) | klo) ^ patA;
        f16x8 x0 = *(const f16x8*)((const char*)h1s + rbase + koff);
        f16x8 x1 = *(const f16x8*)((const char*)h1s + 32768 + rbase + koff);
        f16x8 bn = *(const f16x8*)(Bn + kt * 512);
        an0 = mfma16(x0, bn, an0);  an1 = mfma16(x1, bn, an1);
      }
#pragma unroll
      for (int tl = 0; tl < 2; ++tl) {
        const f32x16 an = tl ? an1 : an0;
#pragma unroll
        for (int q = 0; q < 16; ++q) {
          float rh = (float)g1[c][tl][q >> 3][q & 7];
          g1[c][tl][q >> 3][q & 7] = (f16)tanh_f(an[q] + b2ni[c] + rh);
        }
      }
    }
    __syncthreads();   // all h2_old reads done
    // ---- epi2: in-place h2 update ----
#pragma unroll
    for (int c = 0; c < 2; ++c) {
      const int jxc = 2 * (jw + (c << 5) + colid);
#pragma unroll
      for (int tl = 0; tl < 2; ++tl)
#pragma unroll
        for (int q = 0; q < 16; ++q) {
          const int row = (q & 3) + ((q >> 2) << 3) + (khalf << 2);
          f16* hp = (f16*)((char*)h2s + tl * 32768 + row * 1024 + (jxc ^ ((row & 7) << 4)));
          float zt = (float)g2[c][tl][q >> 3][q & 7];
          float n  = (float)g1[c][tl][q >> 3][q & 7];
          float hold = (float)*hp;
          *hp = (f16)((1.0f - zt) * n + zt * hold);
        }
    }
    __syncthreads();   // h2_new visible

    // ================= FC head: 8 waves x 8 rows, 8-lane shuffle reduce =================
    {
      const int rowg = (wv << 3) + (lane >> 3);   // global row 0..63
      const int tl   = rowg >> 5;
      const int rit  = rowg & 31;
      const int sl   = lane & 7;                  // k-slice of 64
      const char* hb = (const char*)h2s + tl * 32768 + rit * 1024;
      const int pat = (rit & 7) << 4;
      float p0 = 0.f, p1 = 0.f, p2 = 0.f;
#pragma unroll
      for (int j = 0; j < 8; ++j) {
        f16x8 hh = *(const f16x8*)(hb + (((sl << 7) | (j << 4)) ^ pat));
#pragma unroll
        for (int i = 0; i < 8; ++i) {
          const float hf = (float)hh[i];
          const int pos = (i << 6) + (sl << 3) + j;
          p0 = fmaf(hf, fcwT[pos], p0);
          p1 = fmaf(hf, fcwT[512 + pos], p1);
          p2 = fmaf(hf, fcwT[1024 + pos], p2);
        }
      }
#pragma unroll
      for (int m = 1; m < 8; m <<= 1) {
        p0 += __shfl_xor(p0, m, 64);
        p1 += __shfl_xor(p1, m, 64);
        p2 += __shfl_xor(p2, m, 64);
      }
      if (sl == 0) {
        float x0 = xsf[(rowg << 2) + 0] + 0.1f * tanh_f(p0 + fb0);
        float x1 = xsf[(rowg << 2) + 1] + 0.1f * tanh_f(p1 + fb1);
        float x2 = xsf[(rowg << 2) + 2] + 0.1f * tanh_f(p2 + fb2);
        xsf[(rowg << 2) + 0] = x0;  xs16[rowg * 16 + 0] = (f16)x0;
        xsf[(rowg << 2) + 1] = x1;  xs16[rowg * 16 + 1] = (f16)x1;
        xsf[(rowg << 2) + 2] = x2;  xs16[rowg * 16 + 2] = (f16)x2;
        float* op = out + (size_t)(b0 + rowg) * 300 + (size_t)t * 3;
        op[0] = x0; op[1] = x1; op[2] = x2;
      }
    }
    __syncthreads();
  }
}

extern "C" void kernel_launch(void* const* d_in, const int* in_sizes, int n_in,
                              void* d_out, int out_size, void* d_ws, size_t ws_size,
                              hipStream_t stream) {
  const float* z     = (const float*)d_in[0];
  const float* w_ih1 = (const float*)d_in[1];
  const float* w_hh1 = (const float*)d_in[2];
  const float* b_ih1 = (const float*)d_in[3];
  const float* b_hh1 = (const float*)d_in[4];
  const float* w_ih2 = (const float*)d_in[5];
  const float* w_hh2 = (const float*)d_in[6];
  const float* b_ih2 = (const float*)d_in[7];
  const float* b_hh2 = (const float*)d_in[8];
  const float* fc_w  = (const float*)d_in[9];
  const float* fc_b  = (const float*)d_in[10];
  float* out = (float*)d_out;

  f16*   Wp = (f16*)d_ws;                                          // 3 * 1.5 MB packed fp16
  f16*   Wx = (f16*)((char*)d_ws + (size_t)3 * WMAT * 2);          // 48 KB packed w_ih1+bias
  float* Bb = (float*)((char*)d_ws + (size_t)3 * WMAT * 2 + 48 * 512 * 2);

  const int nbatch = in_sizes[0] / 6;

  pack_weights<<<384, 256, 0, stream>>>(w_hh1, Wp);
  pack_weights<<<384, 256, 0, stream>>>(w_ih2, Wp + WMAT);
  pack_weights<<<384, 256, 0, stream>>>(w_hh2, Wp + 2 * WMAT);
  pack_wx<<<12, 256, 0, stream>>>(w_ih1, b_ih1, b_hh1, Wx);
  pack_bias<<<8, 256, 0, stream>>>(b_ih1, b_hh1, Bb);
  pack_bias<<<8, 256, 0, stream>>>(b_ih2, b_hh2, Bb + 2048);

  gru_fused<<<nbatch / 64, 512, 0, stream>>>(z, w_ih1, fc_w, fc_b, Wp, Wx, Bb, out);
}

// Round 10
// 14439.023 us; speedup vs baseline: 2.6837x; 1.5628x over previous
//
#include <hip/hip_runtime.h>

typedef _Float16 f16;
typedef _Float16 f16x8 __attribute__((ext_vector_type(8)));
typedef float f32x16 __attribute__((ext_vector_type(16)));

#define HID   512
#define BT    32          // batch rows per block
#define NSTEP 100
#define WMAT  786432      // halfs per packed weight matrix (1536*512)

__device__ __forceinline__ float sigmoid_f(float x) {
  return 1.0f / (1.0f + __expf(-x));
}
__device__ __forceinline__ float tanh_f(float x) {
  float e = __expf(2.0f * x);
  return 1.0f - 2.0f / (e + 1.0f);
}
__device__ __forceinline__ f32x16 mfma16(f16x8 a, f16x8 b, f32x16 c) {
  return __builtin_amdgcn_mfma_f32_32x32x16_f16(a, b, c, 0, 0, 0);
}
__device__ __forceinline__ f32x16 zero16() {
  f32x16 z;
#pragma unroll
  for (int i = 0; i < 16; ++i) z[i] = 0.f;
  return z;
}

// ---- weight pack: fp32 [1536][512] row-major -> B-fragment-packed fp16 ----
// layout [ct(48)][kt(32)][lane(64)][i(8)]:
//   gate = ct*32 + (lane&31), k = kt*16 + (lane>>5)*8 + i
__global__ void pack_weights(const float* __restrict__ W, f16* __restrict__ out) {
  int t = blockIdx.x * 256 + threadIdx.x;
  if (t >= 48 * 32 * 64) return;
  int lane = t & 63;
  int kt   = (t >> 6) & 31;
  int ct   = t >> 11;
  int gate = ct * 32 + (lane & 31);
  int k0   = kt * 16 + (lane >> 5) * 8;
  const float* src = W + gate * HID + k0;
  f16x8 v;
#pragma unroll
  for (int i = 0; i < 8; ++i) v[i] = (f16)src[i];
  *(f16x8*)(out + (size_t)t * 8) = v;
}

// w_ih1 [1536][3] -> B-fragments padded to K=16 (zeros for k>=3); 48 tiles x 512 halfs
__global__ void pack_wih1(const float* __restrict__ W, f16* __restrict__ out) {
  int t = blockIdx.x * 256 + threadIdx.x;
  if (t >= 48 * 64) return;
  int lane = t & 63;
  int ct   = t >> 6;
  int gate = ct * 32 + (lane & 31);
  int k0   = (lane >> 5) * 8;
  f16x8 v;
#pragma unroll
  for (int i = 0; i < 8; ++i) {
    int k = k0 + i;
    v[i] = (k < 3) ? (f16)W[gate * 3 + k] : (f16)0;
  }
  *(f16x8*)(out + (size_t)t * 8) = v;
}

// combined biases: [0..1023]=bi+bh (r,z), [1024..1535]=bi_n, [1536..2047]=bh_n
__global__ void pack_bias(const float* __restrict__ bi, const float* __restrict__ bh,
                          float* __restrict__ out) {
  int j = blockIdx.x * 256 + threadIdx.x;
  if (j < 1024)      out[j] = bi[j] + bh[j];
  else if (j < 1536) out[j] = bi[j];
  else if (j < 2048) out[j] = bh[j - 512];
}

// Persistent per-block GRU: block = 32 batch rows, 8 waves (2/SIMD), 99 steps.
// PROVEN SPILL-FREE STRUCTURE (round 5): double-buffered h in LDS, epilogues
// write h_new directly to LDS, ZERO register state crosses any barrier or
// kt-loop. This round's single change: kt-loop unroll 2 -> 4 to widen the
// load-scheduling window (R5 was latency-bound: 43% stall, VGPR 100/256).
// h element (row,k) at LDS byte: buf*32768 + row*1024 + ((2k) ^ ((row&7)<<4))
__global__ __launch_bounds__(512, 2) void gru_fused(
    const float* __restrict__ z,
    const float* __restrict__ fc_w,    // [3][512]  fp32
    const float* __restrict__ fc_b,    // [3]
    const f16*  __restrict__ Wp,       // packed Whh1 | Wih2 | Whh2
    const f16*  __restrict__ Wx,       // packed w_ih1 (K=16 padded)
    const float* __restrict__ Bb,      // bias1[2048] | bias2[2048]
    float* __restrict__ out)           // [B][100][3] fp32
{
  __shared__ f16   h1s[2 * BT * HID];   // 64 KB (two 32 KB buffers)
  __shared__ f16   h2s[2 * BT * HID];   // 64 KB
  __shared__ f16   xs16[BT * 16];       // 1 KB  (x as MFMA A-tile, K=16 zero-padded)
  __shared__ float fcwT[3 * HID];       // 6 KB  (fc_w transposed [(k%32)*16 + k/32])
  __shared__ float xsf[BT * 4];         // 0.5 KB (fp32 x state)

  const int tid  = threadIdx.x;
  const int lane = tid & 63;
  const int wv   = tid >> 6;
  const int b0   = blockIdx.x * BT;

  {
    f16x8 z8 = {0, 0, 0, 0, 0, 0, 0, 0};
    for (int i = tid; i < BT * HID / 8; i += 512) {
      ((f16x8*)h1s)[i] = z8;              // zero buffer 0 only
      ((f16x8*)h2s)[i] = z8;
    }
    if (tid < BT * 2) ((f16x8*)xs16)[tid] = z8;
    if (tid < HID) {
      const int pos = ((tid & 31) << 4) + (tid >> 5);
      fcwT[pos]              = fc_w[tid];
      fcwT[512 + pos]        = fc_w[512 + tid];
      fcwT[1024 + pos]       = fc_w[1024 + tid];
    }
  }
  __syncthreads();
  if (tid < BT * 3) {
    const int rr = tid / 3, oo = tid - rr * 3;
    float v = z[(size_t)(b0 + rr) * 6 + 3 + oo];
    xsf[rr * 4 + oo] = v;
    xs16[rr * 16 + oo] = (f16)v;
    out[(size_t)(b0 + rr) * 300 + oo] = v;     // t = 0 output
  }
  __syncthreads();

  const int colid = lane & 31;
  const int khalf = lane >> 5;
  const int klo   = khalf << 4;
  const int patA  = (colid & 7) << 4;
  const int rbase = colid * 1024;
  const int jw    = wv << 6;

  const f16* W1  = Wp;
  const f16* Wi2 = Wp + WMAT;
  const f16* Wh2 = Wp + 2 * WMAT;

  // bias registers (constant over t)
  const int j0 = jw + colid, j1 = jw + 32 + colid;
  const float b1r0 = Bb[j0],         b1r1 = Bb[j1];
  const float b1z0 = Bb[512 + j0],   b1z1 = Bb[512 + j1];
  const float b1ni0 = Bb[1024 + j0], b1ni1 = Bb[1024 + j1];
  const float b1nh0 = Bb[1536 + j0], b1nh1 = Bb[1536 + j1];
  const float b2r0 = Bb[2048 + j0],         b2r1 = Bb[2048 + j1];
  const float b2z0 = Bb[2048 + 512 + j0],   b2z1 = Bb[2048 + 512 + j1];
  const float b2ni0 = Bb[2048 + 1024 + j0], b2ni1 = Bb[2048 + 1024 + j1];
  const float b2nh0 = Bb[2048 + 1536 + j0], b2nh1 = Bb[2048 + 1536 + j1];

  const float fb0 = fc_b[0], fb1 = fc_b[1], fb2 = fc_b[2];
  const int xoff = colid * 32 + klo;

  int p = 0;
  for (int t = 1; t < NSTEP; ++t) {
    const int q = p ^ 1;
    const char* h1r = (const char*)h1s + (p << 15);
    char*       h1w = (char*)h1s + (q << 15);
    const char* h2r = (const char*)h2s + (p << 15);
    char*       h2w = (char*)h2s + (q << 15);

    // ================= GRU layer 1 x 2 chunks: reads h1r + xs16, writes h1w =================
#pragma unroll
    for (int c = 0; c < 2; ++c) {
      const int jb = jw + (c << 5);
      const int ct = jb >> 5;                 // 0..15
      f32x16 aR, aZ, aN, aNx;
      {
        f16x8 ax  = *(const f16x8*)((const char*)xs16 + xoff);
        f16x8 brx = *(const f16x8*)(Wx + (size_t)ct * 512 + lane * 8);
        f16x8 bzx = *(const f16x8*)(Wx + (size_t)(16 + ct) * 512 + lane * 8);
        f16x8 bnx = *(const f16x8*)(Wx + (size_t)(32 + ct) * 512 + lane * 8);
        f32x16 zz = zero16();
        aR  = mfma16(ax, brx, zz);
        aZ  = mfma16(ax, bzx, zz);
        aNx = mfma16(ax, bnx, zz);
        aN  = zz;
      }
      const f16* Br = W1 + (size_t)ct * 16384 + lane * 8;
      const f16* Bz = W1 + (size_t)(16 + ct) * 16384 + lane * 8;
      const f16* Bn = W1 + (size_t)(32 + ct) * 16384 + lane * 8;
#pragma unroll 4
      for (int kt = 0; kt < 32; ++kt) {
        const int koff = ((kt << 5) | klo) ^ patA;
        f16x8 a0 = *(const f16x8*)(h1r + rbase + koff);
        aR = mfma16(a0, *(const f16x8*)(Br + kt * 512), aR);
        aZ = mfma16(a0, *(const f16x8*)(Bz + kt * 512), aZ);
        aN = mfma16(a0, *(const f16x8*)(Bn + kt * 512), aN);
      }
      const float brc  = c ? b1r1 : b1r0;
      const float bzc  = c ? b1z1 : b1z0;
      const float bnic = c ? b1ni1 : b1ni0;
      const float bnhc = c ? b1nh1 : b1nh0;
      const int jx = 2 * (jb + colid);
#pragma unroll
      for (int qq = 0; qq < 16; ++qq) {
        const int row = (qq & 3) + ((qq >> 2) << 3) + (khalf << 2);
        const int off = row * 1024 + (jx ^ ((row & 7) << 4));
        float r  = sigmoid_f(aR[qq] + brc);
        float zt = sigmoid_f(aZ[qq] + bzc);
        float n  = tanh_f(aNx[qq] + bnic + r * (aN[qq] + bnhc));
        float hold = (float)*(const f16*)(h1r + off);
        *(f16*)(h1w + off) = (f16)((1.0f - zt) * n + zt * hold);
      }
    }
    __syncthreads();

    // ================= GRU layer 2 x 2 chunks: reads h1w (new) + h2r, writes h2w =================
#pragma unroll
    for (int c = 0; c < 2; ++c) {
      const int jb = jw + (c << 5);
      const int ct = jb >> 5;
      f32x16 aR = zero16(), aZ = zero16(), aI = zero16(), aH = zero16();
      const f16* Bir = Wi2 + (size_t)ct * 16384 + lane * 8;
      const f16* Biz = Wi2 + (size_t)(16 + ct) * 16384 + lane * 8;
      const f16* Bin = Wi2 + (size_t)(32 + ct) * 16384 + lane * 8;
      const f16* Bhr = Wh2 + (size_t)ct * 16384 + lane * 8;
      const f16* Bhz = Wh2 + (size_t)(16 + ct) * 16384 + lane * 8;
      const f16* Bhn = Wh2 + (size_t)(32 + ct) * 16384 + lane * 8;
#pragma unroll 4
      for (int kt = 0; kt < 32; ++kt) {
        const int koff = ((kt << 5) | klo) ^ patA;
        f16x8 a1 = *(const f16x8*)(h1w + rbase + koff);
        f16x8 a2 = *(const f16x8*)(h2r + rbase + koff);
        aR = mfma16(a1, *(const f16x8*)(Bir + kt * 512), aR);
        aR = mfma16(a2, *(const f16x8*)(Bhr + kt * 512), aR);
        aZ = mfma16(a1, *(const f16x8*)(Biz + kt * 512), aZ);
        aZ = mfma16(a2, *(const f16x8*)(Bhz + kt * 512), aZ);
        aI = mfma16(a1, *(const f16x8*)(Bin + kt * 512), aI);
        aH = mfma16(a2, *(const f16x8*)(Bhn + kt * 512), aH);
      }
      const float brc  = c ? b2r1 : b2r0;
      const float bzc  = c ? b2z1 : b2z0;
      const float bnic = c ? b2ni1 : b2ni0;
      const float bnhc = c ? b2nh1 : b2nh0;
      const int jx = 2 * (jb + colid);
#pragma unroll
      for (int qq = 0; qq < 16; ++qq) {
        const int row = (qq & 3) + ((qq >> 2) << 3) + (khalf << 2);
        const int off = row * 1024 + (jx ^ ((row & 7) << 4));
        float r  = sigmoid_f(aR[qq] + brc);
        float zt = sigmoid_f(aZ[qq] + bzc);
        float n  = tanh_f(aI[qq] + bnic + r * (aH[qq] + bnhc));
        float hold = (float)*(const f16*)(h2r + off);
        *(f16*)(h2w + off) = (f16)((1.0f - zt) * n + zt * hold);
      }
    }
    __syncthreads();

    // ================= FC head: wave-local shuffle reduction =================
    {
      const int row = (wv << 2) + (lane >> 4);   // each wave: 4 rows
      const int sl  = lane & 15;                 // 16 k-slices of 32
      const char* hb = h2w + row * 1024;
      const int pat = (row & 7) << 4;
      float p0 = 0.f, p1 = 0.f, p2 = 0.f;
#pragma unroll
      for (int j = 0; j < 4; ++j) {
        f16x8 hv8 = *(const f16x8*)(hb + ((((sl << 2) + j) << 4) ^ pat));
#pragma unroll
        for (int i = 0; i < 8; ++i) {
          const float hf = (float)hv8[i];
          const int kk = (j << 3) + i;           // k % 32
          p0 = fmaf(hf, fcwT[(kk << 4) + sl], p0);
          p1 = fmaf(hf, fcwT[512 + (kk << 4) + sl], p1);
          p2 = fmaf(hf, fcwT[1024 + (kk << 4) + sl], p2);
        }
      }
#pragma unroll
      for (int m = 1; m < 16; m <<= 1) {
        p0 += __shfl_xor(p0, m, 64);
        p1 += __shfl_xor(p1, m, 64);
        p2 += __shfl_xor(p2, m, 64);
      }
      if (sl == 0) {
        float x0 = xsf[(row << 2) + 0] + 0.1f * tanh_f(p0 + fb0);
        float x1 = xsf[(row << 2) + 1] + 0.1f * tanh_f(p1 + fb1);
        float x2 = xsf[(row << 2) + 2] + 0.1f * tanh_f(p2 + fb2);
        xsf[(row << 2) + 0] = x0;  xs16[row * 16 + 0] = (f16)x0;
        xsf[(row << 2) + 1] = x1;  xs16[row * 16 + 1] = (f16)x1;
        xsf[(row << 2) + 2] = x2;  xs16[row * 16 + 2] = (f16)x2;
        float* op = out + (size_t)(b0 + row) * 300 + (size_t)t * 3;
        op[0] = x0; op[1] = x1; op[2] = x2;
      }
    }
    __syncthreads();
    p ^= 1;
  }
}

extern "C" void kernel_launch(void* const* d_in, const int* in_sizes, int n_in,
                              void* d_out, int out_size, void* d_ws, size_t ws_size,
                              hipStream_t stream) {
  const float* z     = (const float*)d_in[0];
  const float* w_ih1 = (const float*)d_in[1];
  const float* w_hh1 = (const float*)d_in[2];
  const float* b_ih1 = (const float*)d_in[3];
  const float* b_hh1 = (const float*)d_in[4];
  const float* w_ih2 = (const float*)d_in[5];
  const float* w_hh2 = (const float*)d_in[6];
  const float* b_ih2 = (const float*)d_in[7];
  const float* b_hh2 = (const float*)d_in[8];
  const float* fc_w  = (const float*)d_in[9];
  const float* fc_b  = (const float*)d_in[10];
  float* out = (float*)d_out;

  f16*   Wp = (f16*)d_ws;                                          // 3 * 1.5 MB packed fp16
  f16*   Wx = (f16*)((char*)d_ws + (size_t)3 * WMAT * 2);          // 48 KB packed w_ih1
  float* Bb = (float*)((char*)d_ws + (size_t)3 * WMAT * 2 + 48 * 512 * 2);

  const int nbatch = in_sizes[0] / 6;

  pack_weights<<<384, 256, 0, stream>>>(w_hh1, Wp);
  pack_weights<<<384, 256, 0, stream>>>(w_ih2, Wp + WMAT);
  pack_weights<<<384, 256, 0, stream>>>(w_hh2, Wp + 2 * WMAT);
  pack_wih1<<<12, 256, 0, stream>>>(w_ih1, Wx);
  pack_bias<<<8, 256, 0, stream>>>(b_ih1, b_hh1, Bb);
  pack_bias<<<8, 256, 0, stream>>>(b_ih2, b_hh2, Bb + 2048);

  gru_fused<<<nbatch / BT, 512, 0, stream>>>(z, fc_w, fc_b, Wp, Wx, Bb, out);
}

// Round 11
// 13239.661 us; speedup vs baseline: 2.9269x; 1.0906x over previous
//
#include <hip/hip_runtime.h>

typedef _Float16 f16;
typedef _Float16 f16x8 __attribute__((ext_vector_type(8)));
typedef float f32x16 __attribute__((ext_vector_type(16)));

#define HID   512
#define NSTEP 100
#define WMAT  786432      // halfs per packed weight matrix (1536*512)

__device__ __forceinline__ float sigmoid_f(float x) {
  return 1.0f / (1.0f + __expf(-x));
}
__device__ __forceinline__ float tanh_f(float x) {
  float e = __expf(2.0f * x);
  return 1.0f - 2.0f / (e + 1.0f);
}
__device__ __forceinline__ f32x16 mfma16(f16x8 a, f16x8 b, f32x16 c) {
  return __builtin_amdgcn_mfma_f32_32x32x16_f16(a, b, c, 0, 0, 0);
}
__device__ __forceinline__ f32x16 zero16() {
  f32x16 z;
#pragma unroll
  for (int i = 0; i < 16; ++i) z[i] = 0.f;
  return z;
}

// ---- weight pack: fp32 [1536][512] row-major -> B-fragment-packed fp16 ----
// layout [ct(48)][kt(32)][lane(64)][i(8)]:
//   gate = ct*32 + (lane&31), k = kt*16 + (lane>>5)*8 + i
__global__ void pack_weights(const float* __restrict__ W, f16* __restrict__ out) {
  int t = blockIdx.x * 256 + threadIdx.x;
  if (t >= 48 * 32 * 64) return;
  int lane = t & 63;
  int kt   = (t >> 6) & 31;
  int ct   = t >> 11;
  int gate = ct * 32 + (lane & 31);
  int k0   = kt * 16 + (lane >> 5) * 8;
  const float* src = W + gate * HID + k0;
  f16x8 v;
#pragma unroll
  for (int i = 0; i < 8; ++i) v[i] = (f16)src[i];
  *(f16x8*)(out + (size_t)t * 8) = v;
}

// w_ih1 + bias -> K=16 B tiles: slots [w0,w1,w2, bias, 0...]
// bias slot: r,z tiles (ct<32): bi+bh (full combined); n tiles (ct>=32): bi only.
__global__ void pack_wx(const float* __restrict__ W, const float* __restrict__ bi,
                        const float* __restrict__ bh, f16* __restrict__ out) {
  int t = blockIdx.x * 256 + threadIdx.x;
  if (t >= 48 * 64) return;
  int lane = t & 63;
  int ct   = t >> 6;
  int col  = ct * 32 + (lane & 31);
  int k0   = (lane >> 5) * 8;
  f16x8 v;
#pragma unroll
  for (int i = 0; i < 8; ++i) {
    int k = k0 + i;
    float x = 0.f;
    if (k < 3)       x = W[col * 3 + k];
    else if (k == 3) x = (ct < 32) ? (bi[col] + bh[col]) : bi[col];
    v[i] = (f16)x;
  }
  *(f16x8*)(out + (size_t)t * 8) = v;
}

// combined biases: [0..1023]=bi+bh (r,z), [1024..1535]=bi_n, [1536..2047]=bh_n
__global__ void pack_bias(const float* __restrict__ bi, const float* __restrict__ bh,
                          float* __restrict__ out) {
  int j = blockIdx.x * 256 + threadIdx.x;
  if (j < 1024)      out[j] = bi[j] + bh[j];
  else if (j < 1536) out[j] = bi[j];
  else if (j < 2048) out[j] = bh[j - 512];
}

// Persistent per-block GRU, BT=64 (two 32-row tiles share every B-fragment),
// 8 waves x 64 cols, grid=256, ONE generation.
// REGISTER LAW (rounds 1-10): compiler splits 256 regs as 128 arch + 128 acc.
// Parked cross-pass state must live in the ACC half -> gates are parked AS
// f32x16 MFMA accumulators (peak exactly 8 accs = 128), VALU combines touch
// them in place (gfx950 unified file). ZERO arch-class arrays cross any
// kt-loop or barrier. Biases via LDS / K-ext slots, not persistent regs.
// h single-buffered, in-place epilogue (reads own h_old, then overwrites).
// h element (tile,row,k) at LDS byte: tl*32768 + row*1024 + ((2k) ^ ((row&7)<<4))
__global__ __launch_bounds__(512, 2) void gru_fused(
    const float* __restrict__ z,
    const float* __restrict__ fc_w,    // [3][512]  fp32
    const float* __restrict__ fc_b,    // [3]
    const f16*  __restrict__ Wp,       // packed Whh1 | Wih2 | Whh2
    const f16*  __restrict__ Wx,       // packed w_ih1 K-ext tiles (bias in slot 3)
    const float* __restrict__ Bb,      // bias1[2048] | bias2[2048]
    float* __restrict__ out)           // [B][100][3] fp32
{
  __shared__ f16   h1s[64 * HID];       // 64 KB  [tile(2)][row(32)][col(512)]
  __shared__ f16   h2s[64 * HID];       // 64 KB
  __shared__ f16   xs16[64 * 16];       // 2 KB   K-ext A-tile: [x0,x1,x2,1,0..]
  __shared__ float fcwT[3 * HID];       // 6 KB   pos(k) = (k&7)*64 + (k>>3)
  __shared__ float xsf[64 * 4];         // 1 KB   fp32 x state
  __shared__ float bsh[5 * 512];        // 10 KB  [b1nh | b2r | b2z | b2ni | b2nh]

  const int tid  = threadIdx.x;
  const int lane = tid & 63;
  const int wv   = tid >> 6;            // 0..7
  const int b0   = blockIdx.x * 64;

  {
    f16x8 z8 = {0, 0, 0, 0, 0, 0, 0, 0};
    for (int i = tid; i < 64 * HID / 8; i += 512) {
      ((f16x8*)h1s)[i] = z8;
      ((f16x8*)h2s)[i] = z8;
    }
    if (tid < 64) {
#pragma unroll
      for (int k = 0; k < 16; ++k) xs16[tid * 16 + k] = (f16)((k == 3) ? 1.f : 0.f);
    }
    if (tid < HID) {
      const int pos = ((tid & 7) << 6) + (tid >> 3);
      fcwT[pos]        = fc_w[tid];
      fcwT[512 + pos]  = fc_w[512 + tid];
      fcwT[1024 + pos] = fc_w[1024 + tid];
      bsh[tid]         = Bb[1536 + tid];          // b1nh
      bsh[512 + tid]   = Bb[2048 + tid];          // b2r
      bsh[1024 + tid]  = Bb[2048 + 512 + tid];    // b2z
      bsh[1536 + tid]  = Bb[2048 + 1024 + tid];   // b2ni
      bsh[2048 + tid]  = Bb[2048 + 1536 + tid];   // b2nh
    }
  }
  __syncthreads();
  if (tid < 64 * 3) {
    const int rr = tid / 3, oo = tid - rr * 3;
    float v = z[(size_t)(b0 + rr) * 6 + 3 + oo];
    xsf[rr * 4 + oo] = v;
    xs16[rr * 16 + oo] = (f16)v;
    out[(size_t)(b0 + rr) * 300 + oo] = v;     // t = 0 output
  }
  __syncthreads();

  const int colid = lane & 31;
  const int khalf = lane >> 5;
  const int klo   = khalf << 4;
  const int patA  = (colid & 7) << 4;
  const int rbase = colid * 1024;
  const int jw    = wv << 6;            // wave owns cols [jw, jw+64)
  const int ct0   = wv << 1;
  const int ct1   = ct0 + 1;

  const f16* Wi2 = Wp + WMAT;
  const f16* Wh2 = Wp + 2 * WMAT;

  const float fb0 = fc_b[0], fb1 = fc_b[1], fb2 = fc_b[2];
  const int xoff0 = colid * 32 + klo;
  const int xoff1 = (32 + colid) * 32 + klo;

  for (int t = 1; t < NSTEP; ++t) {
    f32x16 aR[2][2], aH[2][2], aZ[2][2];   // acc-class parks only

    // ========== L1 pass r: aR = Whh1_r·h1 + Wx_r·[x|1] (bias in slot) ==========
    {
      f16x8 ax0 = *(const f16x8*)((const char*)xs16 + xoff0);
      f16x8 ax1 = *(const f16x8*)((const char*)xs16 + xoff1);
      f32x16 zz = zero16();
#pragma unroll
      for (int c = 0; c < 2; ++c) {
        f16x8 bx = *(const f16x8*)(Wx + (size_t)(ct0 + c) * 512 + lane * 8);
        aR[c][0] = mfma16(ax0, bx, zz);
        aR[c][1] = mfma16(ax1, bx, zz);
      }
      const f16* B0 = Wp + (size_t)ct0 * 16384 + lane * 8;
      const f16* B1 = Wp + (size_t)ct1 * 16384 + lane * 8;
#pragma unroll 2
      for (int kt = 0; kt < 32; ++kt) {
        const int koff = ((kt << 5) | klo) ^ patA;
        f16x8 a0 = *(const f16x8*)((const char*)h1s + rbase + koff);
        f16x8 a1 = *(const f16x8*)((const char*)h1s + 32768 + rbase + koff);
        f16x8 b0 = *(const f16x8*)(B0 + kt * 512);
        f16x8 b1 = *(const f16x8*)(B1 + kt * 512);
        aR[0][0] = mfma16(a0, b0, aR[0][0]);  aR[0][1] = mfma16(a1, b0, aR[0][1]);
        aR[1][0] = mfma16(a0, b1, aR[1][0]);  aR[1][1] = mfma16(a1, b1, aR[1][1]);
      }
    }
    // ========== L1 pass nH: aH = Whh1_n·h1 ==========
    {
      f32x16 zz = zero16();
      aH[0][0] = zz; aH[0][1] = zz; aH[1][0] = zz; aH[1][1] = zz;
      const f16* B0 = Wp + (size_t)(32 + ct0) * 16384 + lane * 8;
      const f16* B1 = Wp + (size_t)(32 + ct1) * 16384 + lane * 8;
#pragma unroll 2
      for (int kt = 0; kt < 32; ++kt) {
        const int koff = ((kt << 5) | klo) ^ patA;
        f16x8 a0 = *(const f16x8*)((const char*)h1s + rbase + koff);
        f16x8 a1 = *(const f16x8*)((const char*)h1s + 32768 + rbase + koff);
        f16x8 b0 = *(const f16x8*)(B0 + kt * 512);
        f16x8 b1 = *(const f16x8*)(B1 + kt * 512);
        aH[0][0] = mfma16(a0, b0, aH[0][0]);  aH[0][1] = mfma16(a1, b0, aH[0][1]);
        aH[1][0] = mfma16(a0, b1, aH[1][0]);  aH[1][1] = mfma16(a1, b1, aH[1][1]);
      }
    }
    // ---- combine (frees aR): aH <- sigma(aR) * (aH + b1nh); then K-ext adds gi_n + b1ni ----
    {
#pragma unroll
      for (int c = 0; c < 2; ++c) {
        const float bnh = bsh[jw + (c << 5) + colid];
#pragma unroll
        for (int tl = 0; tl < 2; ++tl)
#pragma unroll
          for (int q = 0; q < 16; ++q)
            aH[c][tl][q] = sigmoid_f(aR[c][tl][q]) * (aH[c][tl][q] + bnh);
      }
      f16x8 ax0 = *(const f16x8*)((const char*)xs16 + xoff0);
      f16x8 ax1 = *(const f16x8*)((const char*)xs16 + xoff1);
#pragma unroll
      for (int c = 0; c < 2; ++c) {
        f16x8 bx = *(const f16x8*)(Wx + (size_t)(32 + ct0 + c) * 512 + lane * 8);
        aH[c][0] = mfma16(ax0, bx, aH[c][0]);
        aH[c][1] = mfma16(ax1, bx, aH[c][1]);
      }
    }
    // ========== L1 pass z: aZ = Whh1_z·h1 + Wx_z·[x|1] ==========
    {
      f16x8 ax0 = *(const f16x8*)((const char*)xs16 + xoff0);
      f16x8 ax1 = *(const f16x8*)((const char*)xs16 + xoff1);
      f32x16 zz = zero16();
#pragma unroll
      for (int c = 0; c < 2; ++c) {
        f16x8 bx = *(const f16x8*)(Wx + (size_t)(16 + ct0 + c) * 512 + lane * 8);
        aZ[c][0] = mfma16(ax0, bx, zz);
        aZ[c][1] = mfma16(ax1, bx, zz);
      }
      const f16* B0 = Wp + (size_t)(16 + ct0) * 16384 + lane * 8;
      const f16* B1 = Wp + (size_t)(16 + ct1) * 16384 + lane * 8;
#pragma unroll 2
      for (int kt = 0; kt < 32; ++kt) {
        const int koff = ((kt << 5) | klo) ^ patA;
        f16x8 a0 = *(const f16x8*)((const char*)h1s + rbase + koff);
        f16x8 a1 = *(const f16x8*)((const char*)h1s + 32768 + rbase + koff);
        f16x8 b0 = *(const f16x8*)(B0 + kt * 512);
        f16x8 b1 = *(const f16x8*)(B1 + kt * 512);
        aZ[0][0] = mfma16(a0, b0, aZ[0][0]);  aZ[0][1] = mfma16(a1, b0, aZ[0][1]);
        aZ[1][0] = mfma16(a0, b1, aZ[1][0]);  aZ[1][1] = mfma16(a1, b1, aZ[1][1]);
      }
    }
    __syncthreads();   // all h1_old reads done
    // ---- epi1 (in place): h1 = (1-sigma(aZ))*tanh(aH) + sigma(aZ)*h1_old ----
#pragma unroll
    for (int c = 0; c < 2; ++c) {
      const int jxc = 2 * (jw + (c << 5) + colid);
#pragma unroll
      for (int tl = 0; tl < 2; ++tl)
#pragma unroll
        for (int q = 0; q < 16; ++q) {
          const int row = (q & 3) + ((q >> 2) << 3) + (khalf << 2);
          f16* hp = (f16*)((char*)h1s + tl * 32768 + row * 1024 + (jxc ^ ((row & 7) << 4)));
          float zt = sigmoid_f(aZ[c][tl][q]);
          float n  = tanh_f(aH[c][tl][q]);
          float hold = (float)*hp;
          *hp = (f16)((1.0f - zt) * n + zt * hold);
        }
    }
    __syncthreads();   // h1_new visible

    // ========== L2 pass r: aR = Wi2_r·h1 + Wh2_r·h2 ==========
    {
      f32x16 zz = zero16();
      aR[0][0] = zz; aR[0][1] = zz; aR[1][0] = zz; aR[1][1] = zz;
      const f16* Bi0 = Wi2 + (size_t)ct0 * 16384 + lane * 8;
      const f16* Bi1 = Wi2 + (size_t)ct1 * 16384 + lane * 8;
      const f16* Bh0 = Wh2 + (size_t)ct0 * 16384 + lane * 8;
      const f16* Bh1 = Wh2 + (size_t)ct1 * 16384 + lane * 8;
#pragma unroll 2
      for (int kt = 0; kt < 32; ++kt) {
        const int koff = ((kt << 5) | klo) ^ patA;
        f16x8 x0 = *(const f16x8*)((const char*)h1s + rbase + koff);
        f16x8 x1 = *(const f16x8*)((const char*)h1s + 32768 + rbase + koff);
        f16x8 y0 = *(const f16x8*)((const char*)h2s + rbase + koff);
        f16x8 y1 = *(const f16x8*)((const char*)h2s + 32768 + rbase + koff);
        f16x8 bi0 = *(const f16x8*)(Bi0 + kt * 512);
        f16x8 bi1 = *(const f16x8*)(Bi1 + kt * 512);
        f16x8 bh0 = *(const f16x8*)(Bh0 + kt * 512);
        f16x8 bh1 = *(const f16x8*)(Bh1 + kt * 512);
        aR[0][0] = mfma16(x0, bi0, aR[0][0]);  aR[0][0] = mfma16(y0, bh0, aR[0][0]);
        aR[0][1] = mfma16(x1, bi0, aR[0][1]);  aR[0][1] = mfma16(y1, bh0, aR[0][1]);
        aR[1][0] = mfma16(x0, bi1, aR[1][0]);  aR[1][0] = mfma16(y0, bh1, aR[1][0]);
        aR[1][1] = mfma16(x1, bi1, aR[1][1]);  aR[1][1] = mfma16(y1, bh1, aR[1][1]);
      }
    }
    // ========== L2 pass nH: aH = Wh2_n·h2 ==========
    {
      f32x16 zz = zero16();
      aH[0][0] = zz; aH[0][1] = zz; aH[1][0] = zz; aH[1][1] = zz;
      const f16* B0 = Wh2 + (size_t)(32 + ct0) * 16384 + lane * 8;
      const f16* B1 = Wh2 + (size_t)(32 + ct1) * 16384 + lane * 8;
#pragma unroll 2
      for (int kt = 0; kt < 32; ++kt) {
        const int koff = ((kt << 5) | klo) ^ patA;
        f16x8 y0 = *(const f16x8*)((const char*)h2s + rbase + koff);
        f16x8 y1 = *(const f16x8*)((const char*)h2s + 32768 + rbase + koff);
        f16x8 b0 = *(const f16x8*)(B0 + kt * 512);
        f16x8 b1 = *(const f16x8*)(B1 + kt * 512);
        aH[0][0] = mfma16(y0, b0, aH[0][0]);  aH[0][1] = mfma16(y1, b0, aH[0][1]);
        aH[1][0] = mfma16(y0, b1, aH[1][0]);  aH[1][1] = mfma16(y1, b1, aH[1][1]);
      }
    }
    // ---- combine (frees aR): aH <- sigma(aR + b2r) * (aH + b2nh) ----
#pragma unroll
    for (int c = 0; c < 2; ++c) {
      const int j = jw + (c << 5) + colid;
      const float br  = bsh[512 + j];
      const float bnh = bsh[2048 + j];
#pragma unroll
      for (int tl = 0; tl < 2; ++tl)
#pragma unroll
        for (int q = 0; q < 16; ++q)
          aH[c][tl][q] = sigmoid_f(aR[c][tl][q] + br) * (aH[c][tl][q] + bnh);
    }
    // ========== L2 pass z: aZ = Wi2_z·h1 + Wh2_z·h2 ==========
    {
      f32x16 zz = zero16();
      aZ[0][0] = zz; aZ[0][1] = zz; aZ[1][0] = zz; aZ[1][1] = zz;
      const f16* Bi0 = Wi2 + (size_t)(16 + ct0) * 16384 + lane * 8;
      const f16* Bi1 = Wi2 + (size_t)(16 + ct1) * 16384 + lane * 8;
      const f16* Bh0 = Wh2 + (size_t)(16 + ct0) * 16384 + lane * 8;
      const f16* Bh1 = Wh2 + (size_t)(16 + ct1) * 16384 + lane * 8;
#pragma unroll 2
      for (int kt = 0; kt < 32; ++kt) {
        const int koff = ((kt << 5) | klo) ^ patA;
        f16x8 x0 = *(const f16x8*)((const char*)h1s + rbase + koff);
        f16x8 x1 = *(const f16x8*)((const char*)h1s + 32768 + rbase + koff);
        f16x8 y0 = *(const f16x8*)((const char*)h2s + rbase + koff);
        f16x8 y1 = *(const f16x8*)((const char*)h2s + 32768 + rbase + koff);
        f16x8 bi0 = *(const f16x8*)(Bi0 + kt * 512);
        f16x8 bi1 = *(const f16x8*)(Bi1 + kt * 512);
        f16x8 bh0 = *(const f16x8*)(Bh0 + kt * 512);
        f16x8 bh1 = *(const f16x8*)(Bh1 + kt * 512);
        aZ[0][0] = mfma16(x0, bi0, aZ[0][0]);  aZ[0][0] = mfma16(y0, bh0, aZ[0][0]);
        aZ[0][1] = mfma16(x1, bi0, aZ[0][1]);  aZ[0][1] = mfma16(y1, bh0, aZ[0][1]);
        aZ[1][0] = mfma16(x0, bi1, aZ[1][0]);  aZ[1][0] = mfma16(y0, bh1, aZ[1][0]);
        aZ[1][1] = mfma16(x1, bi1, aZ[1][1]);  aZ[1][1] = mfma16(y1, bh1, aZ[1][1]);
      }
    }
    // ========== L2 pass nI: aH += Wi2_n·h1 (C-operand chaining) ==========
    {
      const f16* B0 = Wi2 + (size_t)(32 + ct0) * 16384 + lane * 8;
      const f16* B1 = Wi2 + (size_t)(32 + ct1) * 16384 + lane * 8;
#pragma unroll 2
      for (int kt = 0; kt < 32; ++kt) {
        const int koff = ((kt << 5) | klo) ^ patA;
        f16x8 x0 = *(const f16x8*)((const char*)h1s + rbase + koff);
        f16x8 x1 = *(const f16x8*)((const char*)h1s + 32768 + rbase + koff);
        f16x8 b0 = *(const f16x8*)(B0 + kt * 512);
        f16x8 b1 = *(const f16x8*)(B1 + kt * 512);
        aH[0][0] = mfma16(x0, b0, aH[0][0]);  aH[0][1] = mfma16(x1, b0, aH[0][1]);
        aH[1][0] = mfma16(x0, b1, aH[1][0]);  aH[1][1] = mfma16(x1, b1, aH[1][1]);
      }
    }
    __syncthreads();   // all h2_old reads done
    // ---- epi2 (in place): h2 = (1-sigma(aZ+b2z))*tanh(aH+b2ni) + sigma(...)*h2_old ----
#pragma unroll
    for (int c = 0; c < 2; ++c) {
      const int j = jw + (c << 5) + colid;
      const float bz  = bsh[1024 + j];
      const float bni = bsh[1536 + j];
      const int jxc = 2 * j;
#pragma unroll
      for (int tl = 0; tl < 2; ++tl)
#pragma unroll
        for (int q = 0; q < 16; ++q) {
          const int row = (q & 3) + ((q >> 2) << 3) + (khalf << 2);
          f16* hp = (f16*)((char*)h2s + tl * 32768 + row * 1024 + (jxc ^ ((row & 7) << 4)));
          float zt = sigmoid_f(aZ[c][tl][q] + bz);
          float n  = tanh_f(aH[c][tl][q] + bni);
          float hold = (float)*hp;
          *hp = (f16)((1.0f - zt) * n + zt * hold);
        }
    }
    __syncthreads();   // h2_new visible

    // ================= FC head: 8 waves x 8 rows, 8-lane shuffle reduce =================
    {
      const int rowg = (wv << 3) + (lane >> 3);   // global row 0..63
      const int tl   = rowg >> 5;
      const int rit  = rowg & 31;
      const int sl   = lane & 7;                  // k-slice of 64
      const char* hb = (const char*)h2s + tl * 32768 + rit * 1024;
      const int pat = (rit & 7) << 4;
      float p0 = 0.f, p1 = 0.f, p2 = 0.f;
#pragma unroll
      for (int j = 0; j < 8; ++j) {
        f16x8 hh = *(const f16x8*)(hb + (((sl << 7) | (j << 4)) ^ pat));
#pragma unroll
        for (int i = 0; i < 8; ++i) {
          const float hf = (float)hh[i];
          const int pos = (i << 6) + (sl << 3) + j;
          p0 = fmaf(hf, fcwT[pos], p0);
          p1 = fmaf(hf, fcwT[512 + pos], p1);
          p2 = fmaf(hf, fcwT[1024 + pos], p2);
        }
      }
#pragma unroll
      for (int m = 1; m < 8; m <<= 1) {
        p0 += __shfl_xor(p0, m, 64);
        p1 += __shfl_xor(p1, m, 64);
        p2 += __shfl_xor(p2, m, 64);
      }
      if (sl == 0) {
        float x0 = xsf[(rowg << 2) + 0] + 0.1f * tanh_f(p0 + fb0);
        float x1 = xsf[(rowg << 2) + 1] + 0.1f * tanh_f(p1 + fb1);
        float x2 = xsf[(rowg << 2) + 2] + 0.1f * tanh_f(p2 + fb2);
        xsf[(rowg << 2) + 0] = x0;  xs16[rowg * 16 + 0] = (f16)x0;
        xsf[(rowg << 2) + 1] = x1;  xs16[rowg * 16 + 1] = (f16)x1;
        xsf[(rowg << 2) + 2] = x2;  xs16[rowg * 16 + 2] = (f16)x2;
        float* op = out + (size_t)(b0 + rowg) * 300 + (size_t)t * 3;
        op[0] = x0; op[1] = x1; op[2] = x2;
      }
    }
    __syncthreads();
  }
}

extern "C" void kernel_launch(void* const* d_in, const int* in_sizes, int n_in,
                              void* d_out, int out_size, void* d_ws, size_t ws_size,
                              hipStream_t stream) {
  const float* z     = (const float*)d_in[0];
  const float* w_ih1 = (const float*)d_in[1];
  const float* w_hh1 = (const float*)d_in[2];
  const float* b_ih1 = (const float*)d_in[3];
  const float* b_hh1 = (const float*)d_in[4];
  const float* w_ih2 = (const float*)d_in[5];
  const float* w_hh2 = (const float*)d_in[6];
  const float* b_ih2 = (const float*)d_in[7];
  const float* b_hh2 = (const float*)d_in[8];
  const float* fc_w  = (const float*)d_in[9];
  const float* fc_b  = (const float*)d_in[10];
  float* out = (float*)d_out;

  f16*   Wp = (f16*)d_ws;                                          // 3 * 1.5 MB packed fp16
  f16*   Wx = (f16*)((char*)d_ws + (size_t)3 * WMAT * 2);          // 48 KB packed w_ih1+bias
  float* Bb = (float*)((char*)d_ws + (size_t)3 * WMAT * 2 + 48 * 512 * 2);

  const int nbatch = in_sizes[0] / 6;

  pack_weights<<<384, 256, 0, stream>>>(w_hh1, Wp);
  pack_weights<<<384, 256, 0, stream>>>(w_ih2, Wp + WMAT);
  pack_weights<<<384, 256, 0, stream>>>(w_hh2, Wp + 2 * WMAT);
  pack_wx<<<12, 256, 0, stream>>>(w_ih1, b_ih1, b_hh1, Wx);
  pack_bias<<<8, 256, 0, stream>>>(b_ih1, b_hh1, Bb);
  pack_bias<<<8, 256, 0, stream>>>(b_ih2, b_hh2, Bb + 2048);

  gru_fused<<<nbatch / 64, 512, 0, stream>>>(z, fc_w, fc_b, Wp, Wx, Bb, out);
}